// Round 1
// baseline (18345.421 us; speedup 1.0000x reference)
//
#include <hip/hip_runtime.h>
#include <stdint.h>

#define Bn 128
#define Tn 256
#define En 300
#define EPn 320          // E padded to multiple of 32 (MFMA K)
#define Hn 1024
#define PADIDX 1

typedef short s16x8 __attribute__((ext_vector_type(8)));
typedef float f32x4 __attribute__((ext_vector_type(4)));

__device__ __forceinline__ unsigned short f2bf(float f) {
  unsigned int u = __builtin_bit_cast(unsigned int, f);
  unsigned int r = (u + 0x7fffu + ((u >> 16) & 1u)) >> 16;  // RNE
  return (unsigned short)r;
}
__device__ __forceinline__ float bf2f(unsigned short h) {
  unsigned int u = ((unsigned int)h) << 16;
  return __builtin_bit_cast(float, u);
}
__device__ __forceinline__ float sigmoidf_(float x) { return 1.f / (1.f + __expf(-x)); }
__device__ __forceinline__ float tanhf_(float x) { return 1.f - 2.f / (__expf(2.f * x) + 1.f); }

// ---------------- K0: lengths -> tstar / padflag ----------------
__global__ void prep_kernel(const int* __restrict__ x, int* __restrict__ tstar,
                            int* __restrict__ padflag) {
  int b = threadIdx.x;
  if (b < Bn) {
    int len = 0;
    for (int t = 0; t < Tn; ++t) len += (x[b * Tn + t] != PADIDX) ? 1 : 0;
    int ts = (len > 0) ? (len - 1) : (Tn - 1);  // jax wraps index -1
    tstar[b] = ts;
    padflag[b] = (x[b * Tn + ts] == PADIDX) ? 1 : 0;
  }
}

// ---------------- K1: inp[t][b][k] = bf16(embed[x[b,t]][k]), k>=300 -> 0 ----
__global__ void gather_kernel(const int* __restrict__ x, const float* __restrict__ embed,
                              unsigned short* __restrict__ inp) {
  int idx = blockIdx.x * 256 + threadIdx.x;   // total = Tn*Bn*EPn
  int k = idx % EPn;
  int rem = idx / EPn;          // t*Bn + b
  int b = rem & (Bn - 1);
  int t = rem >> 7;
  int tok = x[b * Tn + t];
  float v = (k < En) ? embed[(size_t)tok * En + k] : 0.f;
  inp[idx] = f2bf(v);
}

// ---------------- K2: persistent LSTM scan ----------------
// grid = 512 blocks: gid&1 = batch-group (64 batches), gid>>1 = col-block (4 hidden units)
__global__ __launch_bounds__(256, 2) void lstm_scan(
    const float* __restrict__ Whh, const float* __restrict__ Wih,
    const float* __restrict__ bih, const float* __restrict__ bhh,
    const unsigned short* __restrict__ inp, const int* __restrict__ tstar,
    const int* __restrict__ padflag, unsigned short* __restrict__ h_hi,
    unsigned short* __restrict__ h_lo, float* __restrict__ hsel,
    unsigned int* __restrict__ bar) {
  __shared__ unsigned short lds_whh_hi[16 * Hn];   // 32 KB, XOR-swizzled
  __shared__ unsigned short lds_whh_lo[16 * Hn];   // 32 KB
  __shared__ unsigned short lds_wih[16 * EPn];     // 10 KB

  const int gid = blockIdx.x;
  const int group = gid & 1;
  const int cb = gid >> 1;       // 0..255
  const int u0 = cb * 4;         // hidden units u0..u0+3
  const int tid = threadIdx.x;

  // --- convert W_hh slice (rows {gate*H + u0+unit}) into LDS as hi/lo bf16 ---
  for (int i = tid; i < 16 * Hn; i += 256) {
    int c = i >> 10, k = i & (Hn - 1);             // c: 0..15 (unit=c&3, gate=c>>2)
    int grow = (c >> 2) * Hn + u0 + (c & 3);
    float w = Whh[(size_t)grow * Hn + k];
    unsigned short hi = f2bf(w);
    unsigned short lo = f2bf(w - bf2f(hi));
    unsigned int byte = ((unsigned int)(c * 2048 + k * 2)) ^ (((unsigned int)(c & 7)) << 4);
    lds_whh_hi[byte >> 1] = hi;
    lds_whh_lo[byte >> 1] = lo;
  }
  for (int i = tid; i < 16 * EPn; i += 256) {
    int c = i / EPn, k = i - c * EPn;
    int grow = (c >> 2) * Hn + u0 + (c & 3);
    float w = (k < En) ? Wih[(size_t)grow * En + k] : 0.f;
    unsigned int byte = ((unsigned int)(c * (EPn * 2) + k * 2)) ^ (((unsigned int)(c & 7)) << 4);
    lds_wih[byte >> 1] = f2bf(w);
  }
  __syncthreads();

  const int wv = tid >> 6, l = tid & 63;
  const int lr = l & 15;          // A-row / D-col in tile
  const int lq = l >> 4;          // quadrant (k-group / D row-group)
  const int b0w = group * 64 + wv * 16;   // this wave's 16 batch rows
  const int unit = lr & 3, gate = lr >> 2;
  const int gcol = gate * Hn + u0 + unit;
  const float bias = bih[gcol] + bhh[gcol];
  const unsigned int wswz = ((unsigned int)(lr & 7)) << 4;

  int tsr[4], pfr[4];
#pragma unroll
  for (int r = 0; r < 4; ++r) {
    int b = b0w + lq * 4 + r;
    tsr[r] = tstar[b];
    pfr[r] = padflag[b];
  }
  float creg[4] = {0.f, 0.f, 0.f, 0.f};

  for (int t = 0; t < Tn; ++t) {
    const int pin = t & 1, pout = pin ^ 1;
    f32x4 acc = {bias, bias, bias, bias};

    // ---- x-projection: K = 320, single bf16 ----
    const unsigned short* ip = inp + ((size_t)t * Bn + b0w + lr) * EPn + lq * 8;
#pragma unroll
    for (int ks = 0; ks < EPn / 32; ++ks) {
      s16x8 a = *(const s16x8*)(ip + ks * 32);
      unsigned int off = ((unsigned int)(lr * (EPn * 2) + (ks * 32 + lq * 8) * 2)) ^ wswz;
      s16x8 b = *(const s16x8*)((const char*)lds_wih + off);
      acc = __builtin_amdgcn_mfma_f32_16x16x32_bf16(a, b, acc, 0, 0, 0);
    }
    // ---- recurrent part: K = 1024, hi/lo split (3 products) ----
    const unsigned short* hp = h_hi + ((size_t)pin * Bn + b0w + lr) * Hn + lq * 8;
    const unsigned short* lp = h_lo + ((size_t)pin * Bn + b0w + lr) * Hn + lq * 8;
#pragma unroll 4
    for (int ks = 0; ks < 32; ++ks) {
      s16x8 ahi = *(const s16x8*)(hp + ks * 32);
      s16x8 alo = *(const s16x8*)(lp + ks * 32);
      unsigned int off = ((unsigned int)(lr * 2048 + (ks * 32 + lq * 8) * 2)) ^ wswz;
      s16x8 bhi = *(const s16x8*)((const char*)lds_whh_hi + off);
      s16x8 blo = *(const s16x8*)((const char*)lds_whh_lo + off);
      acc = __builtin_amdgcn_mfma_f32_16x16x32_bf16(ahi, bhi, acc, 0, 0, 0);
      acc = __builtin_amdgcn_mfma_f32_16x16x32_bf16(alo, bhi, acc, 0, 0, 0);
      acc = __builtin_amdgcn_mfma_f32_16x16x32_bf16(ahi, blo, acc, 0, 0, 0);
    }

    // ---- gate nonlinearities + state update ----
#pragma unroll
    for (int r = 0; r < 4; ++r) {
      float pre = acc[r];
      float v = (gate == 2) ? tanhf_(pre) : sigmoidf_(pre);
      float vB = __shfl_xor(v, 4);
      float vC = __shfl_xor(v, 8);
      float vD = __shfl_xor(vB, 8);
      // value of gate x (for this (b,unit)) = tmp[x ^ gate], tmp={v,vB,vC,vD}
      float i_ = (gate & 2) ? ((gate & 1) ? vD : vC) : ((gate & 1) ? vB : v);
      float f_ = (gate & 2) ? ((gate & 1) ? vC : vD) : ((gate & 1) ? v : vB);
      float g_ = (gate & 2) ? ((gate & 1) ? vB : v) : ((gate & 1) ? vD : vC);
      float o_ = (gate & 2) ? ((gate & 1) ? v : vB) : ((gate & 1) ? vC : vD);
      float cn = f_ * creg[r] + i_ * g_;
      creg[r] = cn;
      float h = o_ * tanhf_(cn);
      if (gate == 0) {
        int b = b0w + lq * 4 + r;
        int j = u0 + unit;
        unsigned short hh = f2bf(h);
        h_hi[((size_t)pout * Bn + b) * Hn + j] = hh;
        h_lo[((size_t)pout * Bn + b) * Hn + j] = f2bf(h - bf2f(hh));
        if (t == tsr[r]) hsel[(size_t)b * Hn + j] = pfr[r] ? 0.f : h;
      }
    }

    // ---- group barrier (monotonic counter, device scope) ----
    __syncthreads();
    if (tid == 0) {
      __threadfence();                       // release: flush h writes
      atomicAdd(&bar[group], 1u);
      unsigned int target = 256u * (unsigned int)(t + 1);
      unsigned int spins = 0;
      while (__hip_atomic_load(&bar[group], __ATOMIC_ACQUIRE, __HIP_MEMORY_SCOPE_AGENT) <
             target) {
        __builtin_amdgcn_s_sleep(2);
        if (++spins > 200000u) break;        // watchdog: never trips unless deadlock
      }
      __threadfence();                       // acquire: invalidate stale L1/L2
    }
    __syncthreads();
  }
}

// ---------------- K3: out[b][o] = hsel[b]·W_out[o] + b_out[o] ----------------
__global__ void head_kernel(const float* __restrict__ hsel, const float* __restrict__ Wout,
                            const float* __restrict__ bout, float* __restrict__ out) {
  int b = blockIdx.x;
  int l = threadIdx.x;  // 64 threads
  float s0 = 0.f, s1 = 0.f, s2 = 0.f;
  for (int j = l; j < Hn; j += 64) {
    float h = hsel[(size_t)b * Hn + j];
    s0 += h * Wout[j];
    s1 += h * Wout[Hn + j];
    s2 += h * Wout[2 * Hn + j];
  }
#pragma unroll
  for (int m = 32; m; m >>= 1) {
    s0 += __shfl_xor(s0, m);
    s1 += __shfl_xor(s1, m);
    s2 += __shfl_xor(s2, m);
  }
  if (l == 0) {
    out[b * 3 + 0] = s0 + bout[0];
    out[b * 3 + 1] = s1 + bout[1];
    out[b * 3 + 2] = s2 + bout[2];
  }
}

extern "C" void kernel_launch(void* const* d_in, const int* in_sizes, int n_in,
                              void* d_out, int out_size, void* d_ws, size_t ws_size,
                              hipStream_t stream) {
  const int* x = (const int*)d_in[0];
  const float* embed = (const float*)d_in[1];
  const float* Wih = (const float*)d_in[2];
  const float* Whh = (const float*)d_in[3];
  const float* bih = (const float*)d_in[4];
  const float* bhh = (const float*)d_in[5];
  const float* Wout = (const float*)d_in[6];
  const float* bout = (const float*)d_in[7];
  float* out = (float*)d_out;

  // ws layout
  const size_t INP_BYTES = (size_t)Tn * Bn * EPn * 2;       // 20,971,520
  const size_t HBUF_BYTES = (size_t)2 * Bn * Hn * 2;        // 524,288 each (hi, lo)
  const size_t HSEL_BYTES = (size_t)Bn * Hn * 4;            // 524,288
  char* p = (char*)d_ws;
  unsigned short* inp = (unsigned short*)p;             p += INP_BYTES;
  unsigned short* h_hi = (unsigned short*)p;            p += HBUF_BYTES;
  unsigned short* h_lo = (unsigned short*)p;            p += HBUF_BYTES;
  float* hsel = (float*)p;                              p += HSEL_BYTES;
  int* tstar = (int*)p;                                 p += 512;
  int* padflag = (int*)p;                               p += 512;
  unsigned int* bar = (unsigned int*)p;                 p += 256;

  // h(0) = 0 and barrier counters = 0 (every call: graph replays must be self-contained)
  hipMemsetAsync(h_hi, 0, 2 * HBUF_BYTES, stream);  // h_hi and h_lo are contiguous
  hipMemsetAsync(bar, 0, 256, stream);

  prep_kernel<<<1, 128, 0, stream>>>(x, tstar, padflag);
  gather_kernel<<<(Tn * Bn * EPn) / 256, 256, 0, stream>>>(x, embed, inp);
  lstm_scan<<<512, 256, 0, stream>>>(Whh, Wih, bih, bhh, inp, tstar, padflag, h_hi, h_lo,
                                     hsel, bar);
  head_kernel<<<Bn, 64, 0, stream>>>(hsel, Wout, bout, out);
}

// Round 2
// 5891.241 us; speedup vs baseline: 3.1140x; 3.1140x over previous
//
#include <hip/hip_runtime.h>
#include <stdint.h>

#define Bn 128
#define Tn 256
#define En 300
#define EPn 320          // E padded to multiple of 32 (MFMA K)
#define Hn 1024
#define PADIDX 1
#define NBLK 256         // scan grid: 2 groups x 128 col-blocks
#define GSIZE 128        // barrier participants per group

typedef short s16x8 __attribute__((ext_vector_type(8)));
typedef float f32x4 __attribute__((ext_vector_type(4)));

__device__ __forceinline__ unsigned short f2bf(float f) {
  unsigned int u = __builtin_bit_cast(unsigned int, f);
  unsigned int r = (u + 0x7fffu + ((u >> 16) & 1u)) >> 16;  // RNE
  return (unsigned short)r;
}
__device__ __forceinline__ float bf2f(unsigned short h) {
  unsigned int u = ((unsigned int)h) << 16;
  return __builtin_bit_cast(float, u);
}
__device__ __forceinline__ float sigmoidf_(float x) { return 1.f / (1.f + __expf(-x)); }
__device__ __forceinline__ float tanhf_(float x) { return 1.f - 2.f / (__expf(2.f * x) + 1.f); }

// shared gate mixer: lane holds gate `gate` value v for its (b,unit); recover all 4 gates
__device__ __forceinline__ float gate_update(float pre, float& c, int gate) {
  float v = (gate == 2) ? tanhf_(pre) : sigmoidf_(pre);
  float vB = __shfl_xor(v, 4);
  float vC = __shfl_xor(v, 8);
  float vD = __shfl_xor(vB, 8);
  float i_ = (gate & 2) ? ((gate & 1) ? vD : vC) : ((gate & 1) ? vB : v);
  float f_ = (gate & 2) ? ((gate & 1) ? vC : vD) : ((gate & 1) ? v : vB);
  float g_ = (gate & 2) ? ((gate & 1) ? vB : v) : ((gate & 1) ? vD : vC);
  float o_ = (gate & 2) ? ((gate & 1) ? v : vB) : ((gate & 1) ? vC : vD);
  float cn = f_ * c + i_ * g_;
  c = cn;
  return o_ * tanhf_(cn);
}

// ---------------- K0: lengths -> tstar / padflag ----------------
__global__ void prep_kernel(const int* __restrict__ x, int* __restrict__ tstar,
                            int* __restrict__ padflag) {
  int b = threadIdx.x;
  if (b < Bn) {
    int len = 0;
    for (int t = 0; t < Tn; ++t) len += (x[b * Tn + t] != PADIDX) ? 1 : 0;
    int ts = (len > 0) ? (len - 1) : (Tn - 1);  // jax wraps index -1
    tstar[b] = ts;
    padflag[b] = (x[b * Tn + ts] == PADIDX) ? 1 : 0;
  }
}

// ---------------- K1: inp[t][b][k] = bf16(embed[x[b,t]][k]), k>=300 -> 0 ----
__global__ void gather_kernel(const int* __restrict__ x, const float* __restrict__ embed,
                              unsigned short* __restrict__ inp) {
  int idx = blockIdx.x * 256 + threadIdx.x;   // total = Tn*Bn*EPn
  int k = idx % EPn;
  int rem = idx / EPn;          // t*Bn + b
  int b = rem & (Bn - 1);
  int t = rem >> 7;
  int tok = x[b * Tn + t];
  float v = (k < En) ? embed[(size_t)tok * En + k] : 0.f;
  inp[idx] = f2bf(v);
}

// ---------------- K1b: W_ih -> bf16, K padded to 320 ----------------
__global__ void wihcvt_kernel(const float* __restrict__ Wih, unsigned short* __restrict__ wih_bf) {
  int idx = blockIdx.x * 256 + threadIdx.x;   // total = 4096*EPn
  int k = idx % EPn;
  int g = idx / EPn;
  float v = (k < En) ? Wih[(size_t)g * En + k] : 0.f;
  wih_bf[idx] = f2bf(v);
}

// ---------------- K2: persistent LSTM scan ----------------
// 256 blocks x 256 thr. group = XCD/4 (64 batches each); 128 col-blocks per group,
// each owning 8 hidden units (32 gate cols). W_hh hi/lo lives in 128 KB LDS.
__global__ __launch_bounds__(256, 1) void lstm_scan(
    const float* __restrict__ Whh, const unsigned short* __restrict__ wih_bf,
    const float* __restrict__ bih, const float* __restrict__ bhh,
    const unsigned short* __restrict__ inp, const int* __restrict__ tstar,
    const int* __restrict__ padflag, unsigned short* __restrict__ h_hi,
    unsigned short* __restrict__ h_lo, float* __restrict__ hsel,
    unsigned int* __restrict__ bar) {
  __shared__ unsigned short lds_hi[32 * Hn];   // 64 KB, XOR-swizzled rows
  __shared__ unsigned short lds_lo[32 * Hn];   // 64 KB

  const int bid = blockIdx.x;
  const int xcd = bid & 7;                 // assumed round-robin block->XCD (perf-only)
  const int group = xcd >> 2;              // XCDs 0-3 -> group 0, 4-7 -> group 1
  const int cb = ((xcd & 3) << 5) | (bid >> 3);   // 0..127, bijective per group
  const int u0 = cb * 8;                   // 8 hidden units per block
  const int tid = threadIdx.x;

  // --- convert W_hh slice into LDS hi/lo (row c = ct*16 + gate*4 + usub) ---
  for (int i = tid; i < 32 * Hn; i += 256) {
    int c = i >> 10, k = i & (Hn - 1);
    int grow = ((c >> 2) & 3) * Hn + u0 + ((c >> 4) << 2) + (c & 3);
    float w = Whh[(size_t)grow * Hn + k];
    unsigned short hi = f2bf(w);
    unsigned short lo = f2bf(w - bf2f(hi));
    unsigned int byte = ((unsigned int)(c * 2048 + k * 2)) ^ (((unsigned int)(c & 7)) << 4);
    lds_hi[byte >> 1] = hi;
    lds_lo[byte >> 1] = lo;
  }
  __syncthreads();

  const int wv = tid >> 6, l = tid & 63;
  const int lr = l & 15;                    // A-row (batch) / D-col in tile
  const int lq = l >> 4;                    // quadrant
  const int usub = lr & 3, gate = lr >> 2;
  const int b0w = group * 64 + wv * 16;     // this wave's 16 batch rows
  const unsigned int wswz = ((unsigned int)(lr & 7)) << 4;
  const int col0 = gate * Hn + u0 + usub;   // ct=0 gate column; ct=1 is col0+4
  const float bias0 = bih[col0] + bhh[col0];
  const float bias1 = bih[col0 + 4] + bhh[col0 + 4];

  int tsr[4], pfr[4];
#pragma unroll
  for (int r = 0; r < 4; ++r) {
    int b = b0w + lq * 4 + r;
    tsr[r] = tstar[b];
    pfr[r] = padflag[b];
  }
  float creg0[4] = {0.f, 0.f, 0.f, 0.f};
  float creg1[4] = {0.f, 0.f, 0.f, 0.f};

  for (int t = 0; t < Tn; ++t) {
    const int pin = t & 1, pout = pin ^ 1;
    f32x4 acc0 = {bias0, bias0, bias0, bias0};
    f32x4 acc1 = {bias1, bias1, bias1, bias1};

    // ---- x-projection: K = 320, single bf16, W_ih from global (L1/L2-hot) ----
    const unsigned short* ip = inp + ((size_t)t * Bn + b0w + lr) * EPn + lq * 8;
    const unsigned short* wp0 = wih_bf + (size_t)col0 * EPn + lq * 8;
#pragma unroll
    for (int ks = 0; ks < EPn / 32; ++ks) {
      s16x8 a = *(const s16x8*)(ip + ks * 32);
      s16x8 b0 = *(const s16x8*)(wp0 + ks * 32);
      s16x8 b1 = *(const s16x8*)(wp0 + 4 * EPn + ks * 32);
      acc0 = __builtin_amdgcn_mfma_f32_16x16x32_bf16(a, b0, acc0, 0, 0, 0);
      acc1 = __builtin_amdgcn_mfma_f32_16x16x32_bf16(a, b1, acc1, 0, 0, 0);
    }
    // ---- recurrent: K = 1024, hi/lo split (3 products), W from LDS ----
    const unsigned short* hp = h_hi + ((size_t)pin * Bn + b0w + lr) * Hn + lq * 8;
    const unsigned short* lp = h_lo + ((size_t)pin * Bn + b0w + lr) * Hn + lq * 8;
    const char* base_hi = (const char*)lds_hi;
    const char* base_lo = (const char*)lds_lo;
#pragma unroll 4
    for (int ks = 0; ks < 32; ++ks) {
      s16x8 ahi = *(const s16x8*)(hp + ks * 32);
      s16x8 alo = *(const s16x8*)(lp + ks * 32);
      unsigned int o0 = ((unsigned int)(lr * 2048 + (ks * 32 + lq * 8) * 2)) ^ wswz;
      unsigned int o1 = o0 + 32768;   // ct=1: row += 16 (swizzle bits unaffected)
      s16x8 bh0 = *(const s16x8*)(base_hi + o0);
      s16x8 bl0 = *(const s16x8*)(base_lo + o0);
      s16x8 bh1 = *(const s16x8*)(base_hi + o1);
      s16x8 bl1 = *(const s16x8*)(base_lo + o1);
      acc0 = __builtin_amdgcn_mfma_f32_16x16x32_bf16(ahi, bh0, acc0, 0, 0, 0);
      acc1 = __builtin_amdgcn_mfma_f32_16x16x32_bf16(ahi, bh1, acc1, 0, 0, 0);
      acc0 = __builtin_amdgcn_mfma_f32_16x16x32_bf16(alo, bh0, acc0, 0, 0, 0);
      acc1 = __builtin_amdgcn_mfma_f32_16x16x32_bf16(alo, bh1, acc1, 0, 0, 0);
      acc0 = __builtin_amdgcn_mfma_f32_16x16x32_bf16(ahi, bl0, acc0, 0, 0, 0);
      acc1 = __builtin_amdgcn_mfma_f32_16x16x32_bf16(ahi, bl1, acc1, 0, 0, 0);
    }

    // ---- gates + state update (both col-tiles) ----
#pragma unroll
    for (int r = 0; r < 4; ++r) {
      float h0 = gate_update(acc0[r], creg0[r], gate);
      float h1 = gate_update(acc1[r], creg1[r], gate);
      if (gate == 0) {
        int b = b0w + lq * 4 + r;
        size_t rowo = ((size_t)pout * Bn + b) * Hn;
        int j0 = u0 + usub, j1 = j0 + 4;
        unsigned short hh0 = f2bf(h0);
        h_hi[rowo + j0] = hh0;
        h_lo[rowo + j0] = f2bf(h0 - bf2f(hh0));
        unsigned short hh1 = f2bf(h1);
        h_hi[rowo + j1] = hh1;
        h_lo[rowo + j1] = f2bf(h1 - bf2f(hh1));
        if (t == tsr[r]) {
          hsel[(size_t)b * Hn + j0] = pfr[r] ? 0.f : h0;
          hsel[(size_t)b * Hn + j1] = pfr[r] ? 0.f : h1;
        }
      }
    }

    // ---- group barrier: one wbl2 + one inv per block per step, relaxed spins ----
    __syncthreads();                    // all waves' stores drained (vmcnt before s_barrier)
    if (tid == 0) {
      __builtin_amdgcn_fence(__ATOMIC_RELEASE, "agent");   // wb L2 once
      __hip_atomic_fetch_add(&bar[group], 1u, __ATOMIC_RELAXED, __HIP_MEMORY_SCOPE_AGENT);
      unsigned int target = (unsigned int)GSIZE * (unsigned int)(t + 1);
      unsigned int spins = 0;
      while (__hip_atomic_load(&bar[group], __ATOMIC_RELAXED, __HIP_MEMORY_SCOPE_AGENT) <
             target) {
        __builtin_amdgcn_s_sleep(4);
        if (++spins > 3000000u) break;  // watchdog: dead unless deadlock
      }
      __builtin_amdgcn_fence(__ATOMIC_ACQUIRE, "agent");   // inv L2 once
    }
    __syncthreads();
  }
}

// ---------------- K3: out[b][o] = hsel[b]·W_out[o] + b_out[o] ----------------
__global__ void head_kernel(const float* __restrict__ hsel, const float* __restrict__ Wout,
                            const float* __restrict__ bout, float* __restrict__ out) {
  int b = blockIdx.x;
  int l = threadIdx.x;  // 64 threads
  float s0 = 0.f, s1 = 0.f, s2 = 0.f;
  for (int j = l; j < Hn; j += 64) {
    float h = hsel[(size_t)b * Hn + j];
    s0 += h * Wout[j];
    s1 += h * Wout[Hn + j];
    s2 += h * Wout[2 * Hn + j];
  }
#pragma unroll
  for (int m = 32; m; m >>= 1) {
    s0 += __shfl_xor(s0, m);
    s1 += __shfl_xor(s1, m);
    s2 += __shfl_xor(s2, m);
  }
  if (l == 0) {
    out[b * 3 + 0] = s0 + bout[0];
    out[b * 3 + 1] = s1 + bout[1];
    out[b * 3 + 2] = s2 + bout[2];
  }
}

extern "C" void kernel_launch(void* const* d_in, const int* in_sizes, int n_in,
                              void* d_out, int out_size, void* d_ws, size_t ws_size,
                              hipStream_t stream) {
  const int* x = (const int*)d_in[0];
  const float* embed = (const float*)d_in[1];
  const float* Wih = (const float*)d_in[2];
  const float* Whh = (const float*)d_in[3];
  const float* bih = (const float*)d_in[4];
  const float* bhh = (const float*)d_in[5];
  const float* Wout = (const float*)d_in[6];
  const float* bout = (const float*)d_in[7];
  float* out = (float*)d_out;

  // ws layout
  const size_t INP_BYTES = (size_t)Tn * Bn * EPn * 2;       // 20,971,520
  const size_t WIH_BYTES = (size_t)4 * Hn * EPn * 2;        // 2,621,440
  const size_t HBUF_BYTES = (size_t)2 * Bn * Hn * 2;        // 524,288 each (hi, lo)
  const size_t HSEL_BYTES = (size_t)Bn * Hn * 4;            // 524,288
  char* p = (char*)d_ws;
  unsigned short* inp = (unsigned short*)p;             p += INP_BYTES;
  unsigned short* wih_bf = (unsigned short*)p;          p += WIH_BYTES;
  unsigned short* h_hi = (unsigned short*)p;            p += HBUF_BYTES;
  unsigned short* h_lo = (unsigned short*)p;            p += HBUF_BYTES;
  float* hsel = (float*)p;                              p += HSEL_BYTES;
  int* tstar = (int*)p;                                 p += 512;
  int* padflag = (int*)p;                               p += 512;
  unsigned int* bar = (unsigned int*)p;                 p += 256;

  // h(0) = 0 and barrier counters = 0 (graph replays rerun these; self-contained)
  hipMemsetAsync(h_hi, 0, 2 * HBUF_BYTES, stream);  // h_hi and h_lo are contiguous
  hipMemsetAsync(bar, 0, 256, stream);

  prep_kernel<<<1, 128, 0, stream>>>(x, tstar, padflag);
  gather_kernel<<<(Tn * Bn * EPn) / 256, 256, 0, stream>>>(x, embed, inp);
  wihcvt_kernel<<<(4 * Hn * EPn) / 256, 256, 0, stream>>>(Wih, wih_bf);
  lstm_scan<<<NBLK, 256, 0, stream>>>(Whh, wih_bf, bih, bhh, inp, tstar, padflag, h_hi,
                                      h_lo, hsel, bar);
  head_kernel<<<Bn, 64, 0, stream>>>(hsel, Wout, bout, out);
}

// Round 3
// 5023.532 us; speedup vs baseline: 3.6519x; 1.1727x over previous
//
#include <hip/hip_runtime.h>
#include <stdint.h>

#define Bn 128
#define Tn 256
#define En 300
#define EPn 320          // E padded to multiple of 32 (MFMA K)
#define Hn 1024
#define PADIDX 1
#define NBLK 256         // 2 groups x 128 col-blocks
#define GSIZE 128        // barrier participants per group

typedef short s16x8 __attribute__((ext_vector_type(8)));
typedef float f32x4 __attribute__((ext_vector_type(4)));
typedef unsigned long long u64;
typedef unsigned int u32;

#define LDQ(p) __hip_atomic_load((p), __ATOMIC_RELAXED, __HIP_MEMORY_SCOPE_SYSTEM)
#define ST32(p, v) __hip_atomic_store((p), (v), __ATOMIC_RELAXED, __HIP_MEMORY_SCOPE_SYSTEM)

__device__ __forceinline__ unsigned short f2bf(float f) {
  u32 u = __builtin_bit_cast(u32, f);
  u32 r = (u + 0x7fffu + ((u >> 16) & 1u)) >> 16;  // RNE
  return (unsigned short)r;
}
__device__ __forceinline__ float bf2f(unsigned short h) {
  u32 u = ((u32)h) << 16;
  return __builtin_bit_cast(float, u);
}
__device__ __forceinline__ float sigmoidf_(float x) { return 1.f / (1.f + __expf(-x)); }
__device__ __forceinline__ float tanhf_(float x) { return 1.f - 2.f / (__expf(2.f * x) + 1.f); }

__device__ __forceinline__ s16x8 mkv(u64 a, u64 b) {
  union { u64 q[2]; s16x8 v; } u;
  u.q[0] = a; u.q[1] = b;
  return u.v;
}

// lane holds gate `gate` value v for its (b,unit); recover all 4 gates via shfl
__device__ __forceinline__ float gate_update(float pre, float& c, int gate) {
  float v = (gate == 2) ? tanhf_(pre) : sigmoidf_(pre);
  float vB = __shfl_xor(v, 4);
  float vC = __shfl_xor(v, 8);
  float vD = __shfl_xor(vB, 8);
  float i_ = (gate & 2) ? ((gate & 1) ? vD : vC) : ((gate & 1) ? vB : v);
  float f_ = (gate & 2) ? ((gate & 1) ? vC : vD) : ((gate & 1) ? v : vB);
  float g_ = (gate & 2) ? ((gate & 1) ? vB : v) : ((gate & 1) ? vD : vC);
  float o_ = (gate & 2) ? ((gate & 1) ? v : vB) : ((gate & 1) ? vC : vD);
  float cn = f_ * c + i_ * g_;
  c = cn;
  return o_ * tanhf_(cn);
}

// ---------------- K0: lengths -> tstar / padflag ----------------
__global__ void prep_kernel(const int* __restrict__ x, int* __restrict__ tstar,
                            int* __restrict__ padflag) {
  int b = threadIdx.x;
  if (b < Bn) {
    int len = 0;
    for (int t = 0; t < Tn; ++t) len += (x[b * Tn + t] != PADIDX) ? 1 : 0;
    int ts = (len > 0) ? (len - 1) : (Tn - 1);  // jax wraps index -1
    tstar[b] = ts;
    padflag[b] = (x[b * Tn + ts] == PADIDX) ? 1 : 0;
  }
}

// ---------------- K1: inp[t][b][k] = bf16(embed[x[b,t]][k]), k>=300 -> 0 ----
__global__ void gather_kernel(const int* __restrict__ x, const float* __restrict__ embed,
                              unsigned short* __restrict__ inp) {
  int idx = blockIdx.x * 256 + threadIdx.x;   // total = Tn*Bn*EPn
  int k = idx % EPn;
  int rem = idx / EPn;          // t*Bn + b
  int b = rem & (Bn - 1);
  int t = rem >> 7;
  int tok = x[b * Tn + t];
  float v = (k < En) ? embed[(size_t)tok * En + k] : 0.f;
  inp[idx] = f2bf(v);
}

// ---------------- K1b: W_ih -> bf16, K padded to 320 ----------------
__global__ void wihcvt_kernel(const float* __restrict__ Wih, unsigned short* __restrict__ wih_bf) {
  int idx = blockIdx.x * 256 + threadIdx.x;   // total = 4096*EPn
  int k = idx % EPn;
  int g = idx / EPn;
  float v = (k < En) ? Wih[(size_t)g * En + k] : 0.f;
  wih_bf[idx] = f2bf(v);
}

// ---------------- K2: persistent LSTM scan ----------------
// 256 blocks x 256 thr. group = bid>>7 (64 batches); 128 col-blocks per group,
// each owning 8 hidden units (32 gate cols). W_hh hi/lo in 128 KB LDS.
// h is fine-grained-coherent (sc0sc1 stores/loads via system-scope atomics);
// barrier is a pure monotonic counter — NO cache-walk fences anywhere.
__global__ __launch_bounds__(256, 1) void lstm_scan(
    const float* __restrict__ Whh, const unsigned short* __restrict__ wih_bf,
    const float* __restrict__ bih, const float* __restrict__ bhh,
    const unsigned short* __restrict__ inp, const int* __restrict__ tstar,
    const int* __restrict__ padflag, unsigned short* __restrict__ h_hi,
    unsigned short* __restrict__ h_lo, float* __restrict__ hsel,
    unsigned int* __restrict__ bar) {
  __shared__ unsigned short lds_hi[32 * Hn];   // 64 KB, XOR-swizzled rows
  __shared__ unsigned short lds_lo[32 * Hn];   // 64 KB

  const int bid = blockIdx.x;
  const int group = bid >> 7;              // 0: batches 0-63, 1: batches 64-127
  const int cb = bid & 127;                // col-block within group
  const int u0 = cb * 8;                   // 8 hidden units per block
  const int tid = threadIdx.x;

  // --- convert W_hh slice into LDS hi/lo (row c = ct*16 + gate*4 + usub) ---
  for (int i = tid; i < 32 * Hn; i += 256) {
    int c = i >> 10, k = i & (Hn - 1);
    int grow = ((c >> 2) & 3) * Hn + u0 + ((c >> 4) << 2) + (c & 3);
    float w = Whh[(size_t)grow * Hn + k];
    unsigned short hi = f2bf(w);
    unsigned short lo = f2bf(w - bf2f(hi));
    u32 byte = ((u32)(c * 2048 + k * 2)) ^ (((u32)(c & 7)) << 4);
    lds_hi[byte >> 1] = hi;
    lds_lo[byte >> 1] = lo;
  }
  __syncthreads();

  const int wv = tid >> 6, l = tid & 63;
  const int lr = l & 15;                    // A-row (batch) / D-col in tile
  const int lq = l >> 4;                    // quadrant
  const int usub = lr & 3, gate = lr >> 2;
  const int b0w = group * 64 + wv * 16;     // this wave's 16 batch rows
  const u32 wswz = ((u32)(lr & 7)) << 4;
  const int col0 = gate * Hn + u0 + usub;   // ct=0 gate column; ct=1 is col0+4
  const float bias0 = bih[col0] + bhh[col0];
  const float bias1 = bih[col0 + 4] + bhh[col0 + 4];
  const int lq2 = lq * 2;

  int tsr[4], pfr[4];
#pragma unroll
  for (int r = 0; r < 4; ++r) {
    int b = b0w + lq * 4 + r;
    tsr[r] = tstar[b];
    pfr[r] = padflag[b];
  }
  float creg0[4] = {0.f, 0.f, 0.f, 0.f};
  float creg1[4] = {0.f, 0.f, 0.f, 0.f};

  const char* base_hi = (const char*)lds_hi;
  const char* base_lo = (const char*)lds_lo;

  for (int t = 0; t < Tn; ++t) {
    const int pin = t & 1, pout = pin ^ 1;
    f32x4 acc0 = {bias0, bias0, bias0, bias0};
    f32x4 acc1 = {bias1, bias1, bias1, bias1};

    // ---- x-projection: K = 320, single bf16, normal cached loads ----
    const unsigned short* ip = inp + ((size_t)t * Bn + b0w + lr) * EPn + lq * 8;
    const unsigned short* wp0 = wih_bf + (size_t)col0 * EPn + lq * 8;
#pragma unroll
    for (int ks = 0; ks < EPn / 32; ++ks) {
      s16x8 a = *(const s16x8*)(ip + ks * 32);
      s16x8 b0 = *(const s16x8*)(wp0 + ks * 32);
      s16x8 b1 = *(const s16x8*)(wp0 + 4 * EPn + ks * 32);
      acc0 = __builtin_amdgcn_mfma_f32_16x16x32_bf16(a, b0, acc0, 0, 0, 0);
      acc1 = __builtin_amdgcn_mfma_f32_16x16x32_bf16(a, b1, acc1, 0, 0, 0);
    }

    // ---- recurrent: K = 1024, hi/lo split, h via coherent (sc0sc1) u64 loads,
    //      2-deep 4-ks register chunk pipeline (16 loads in flight) ----
    const u64* hp = (const u64*)(h_hi + ((size_t)pin * Bn + b0w + lr) * Hn);
    const u64* lp = (const u64*)(h_lo + ((size_t)pin * Bn + b0w + lr) * Hn);

    u64 cka[16], ckb[16];
#define LOAD_CHUNK(C, KC)                                \
  _Pragma("unroll") for (int i = 0; i < 4; ++i) {        \
    int o = ((KC) * 4 + i) * 8 + lq2;                    \
    C[4 * i + 0] = LDQ(hp + o);                          \
    C[4 * i + 1] = LDQ(hp + o + 1);                      \
    C[4 * i + 2] = LDQ(lp + o);                          \
    C[4 * i + 3] = LDQ(lp + o + 1);                      \
  }
#define BODY(C, KC)                                                                   \
  _Pragma("unroll") for (int i = 0; i < 4; ++i) {                                     \
    int ks = (KC) * 4 + i;                                                            \
    s16x8 ahi = mkv(C[4 * i + 0], C[4 * i + 1]);                                      \
    s16x8 alo = mkv(C[4 * i + 2], C[4 * i + 3]);                                      \
    u32 o0 = ((u32)(lr * 2048 + (ks * 32 + lq * 8) * 2)) ^ wswz;                      \
    u32 o1 = o0 + 32768;                                                              \
    s16x8 bh0 = *(const s16x8*)(base_hi + o0);                                        \
    s16x8 bl0 = *(const s16x8*)(base_lo + o0);                                        \
    s16x8 bh1 = *(const s16x8*)(base_hi + o1);                                        \
    s16x8 bl1 = *(const s16x8*)(base_lo + o1);                                        \
    acc0 = __builtin_amdgcn_mfma_f32_16x16x32_bf16(ahi, bh0, acc0, 0, 0, 0);          \
    acc1 = __builtin_amdgcn_mfma_f32_16x16x32_bf16(ahi, bh1, acc1, 0, 0, 0);          \
    acc0 = __builtin_amdgcn_mfma_f32_16x16x32_bf16(alo, bh0, acc0, 0, 0, 0);          \
    acc1 = __builtin_amdgcn_mfma_f32_16x16x32_bf16(alo, bh1, acc1, 0, 0, 0);          \
    acc0 = __builtin_amdgcn_mfma_f32_16x16x32_bf16(ahi, bl0, acc0, 0, 0, 0);          \
    acc1 = __builtin_amdgcn_mfma_f32_16x16x32_bf16(ahi, bl1, acc1, 0, 0, 0);          \
  }

    LOAD_CHUNK(cka, 0)
    LOAD_CHUNK(ckb, 1)
    BODY(cka, 0) LOAD_CHUNK(cka, 2)
    BODY(ckb, 1) LOAD_CHUNK(ckb, 3)
    BODY(cka, 2) LOAD_CHUNK(cka, 4)
    BODY(ckb, 3) LOAD_CHUNK(ckb, 5)
    BODY(cka, 4) LOAD_CHUNK(cka, 6)
    BODY(ckb, 5) LOAD_CHUNK(ckb, 7)
    BODY(cka, 6)
    BODY(ckb, 7)
#undef LOAD_CHUNK
#undef BODY

    // ---- gates + state update (both col-tiles) ----
#pragma unroll
    for (int r = 0; r < 4; ++r) {
      float h0 = gate_update(acc0[r], creg0[r], gate);
      float h1 = gate_update(acc1[r], creg1[r], gate);
      // hi/lo bf16 split + pair-pack across usub lanes (convergent shfls)
      unsigned short h0h = f2bf(h0);
      unsigned short h0l = f2bf(h0 - bf2f(h0h));
      unsigned short h1h = f2bf(h1);
      unsigned short h1l = f2bf(h1 - bf2f(h1h));
      u32 n0h = (u32)__shfl_xor((int)(u32)h0h, 1);
      u32 n0l = (u32)__shfl_xor((int)(u32)h0l, 1);
      u32 n1h = (u32)__shfl_xor((int)(u32)h1h, 1);
      u32 n1l = (u32)__shfl_xor((int)(u32)h1l, 1);
      if (gate == 0) {
        int b = b0w + lq * 4 + r;
        size_t rowo = ((size_t)pout * Bn + b) * Hn;
        int j0 = u0 + usub, j1 = j0 + 4;
        if ((usub & 1) == 0) {  // even usub stores the (j, j+1) pair as one dword
          ST32((u32*)(h_hi + rowo + j0), (u32)h0h | (n0h << 16));
          ST32((u32*)(h_lo + rowo + j0), (u32)h0l | (n0l << 16));
          ST32((u32*)(h_hi + rowo + j1), (u32)h1h | (n1h << 16));
          ST32((u32*)(h_lo + rowo + j1), (u32)h1l | (n1l << 16));
        }
        if (t == tsr[r]) {
          hsel[(size_t)b * Hn + j0] = pfr[r] ? 0.f : h0;
          hsel[(size_t)b * Hn + j1] = pfr[r] ? 0.f : h1;
        }
      }
    }

    // ---- group barrier: pure counter, no cache maintenance ----
    __syncthreads();   // drains vmcnt -> sc1 h-stores complete at coherence point
    if (tid == 0) {
      __hip_atomic_fetch_add(&bar[group * 32], 1u, __ATOMIC_RELAXED,
                             __HIP_MEMORY_SCOPE_SYSTEM);
      u32 target = (u32)GSIZE * (u32)(t + 1);
      u32 spins = 0;
      while (__hip_atomic_load(&bar[group * 32], __ATOMIC_RELAXED,
                               __HIP_MEMORY_SCOPE_SYSTEM) < target) {
        __builtin_amdgcn_s_sleep(8);
        if (++spins > 500000u) break;  // watchdog: dead unless deadlock
      }
    }
    __syncthreads();
  }
}

// ---------------- K3: out[b][o] = hsel[b]·W_out[o] + b_out[o] ----------------
__global__ void head_kernel(const float* __restrict__ hsel, const float* __restrict__ Wout,
                            const float* __restrict__ bout, float* __restrict__ out) {
  int b = blockIdx.x;
  int l = threadIdx.x;  // 64 threads
  float s0 = 0.f, s1 = 0.f, s2 = 0.f;
  for (int j = l; j < Hn; j += 64) {
    float h = hsel[(size_t)b * Hn + j];
    s0 += h * Wout[j];
    s1 += h * Wout[Hn + j];
    s2 += h * Wout[2 * Hn + j];
  }
#pragma unroll
  for (int m = 32; m; m >>= 1) {
    s0 += __shfl_xor(s0, m);
    s1 += __shfl_xor(s1, m);
    s2 += __shfl_xor(s2, m);
  }
  if (l == 0) {
    out[b * 3 + 0] = s0 + bout[0];
    out[b * 3 + 1] = s1 + bout[1];
    out[b * 3 + 2] = s2 + bout[2];
  }
}

extern "C" void kernel_launch(void* const* d_in, const int* in_sizes, int n_in,
                              void* d_out, int out_size, void* d_ws, size_t ws_size,
                              hipStream_t stream) {
  const int* x = (const int*)d_in[0];
  const float* embed = (const float*)d_in[1];
  const float* Wih = (const float*)d_in[2];
  const float* Whh = (const float*)d_in[3];
  const float* bih = (const float*)d_in[4];
  const float* bhh = (const float*)d_in[5];
  const float* Wout = (const float*)d_in[6];
  const float* bout = (const float*)d_in[7];
  float* out = (float*)d_out;

  // ws layout
  const size_t INP_BYTES = (size_t)Tn * Bn * EPn * 2;       // 20,971,520
  const size_t WIH_BYTES = (size_t)4 * Hn * EPn * 2;        // 2,621,440
  const size_t HBUF_BYTES = (size_t)2 * Bn * Hn * 2;        // 524,288 each (hi, lo)
  const size_t HSEL_BYTES = (size_t)Bn * Hn * 4;            // 524,288
  char* p = (char*)d_ws;
  unsigned short* inp = (unsigned short*)p;             p += INP_BYTES;
  unsigned short* wih_bf = (unsigned short*)p;          p += WIH_BYTES;
  unsigned short* h_hi = (unsigned short*)p;            p += HBUF_BYTES;
  unsigned short* h_lo = (unsigned short*)p;            p += HBUF_BYTES;
  float* hsel = (float*)p;                              p += HSEL_BYTES;
  int* tstar = (int*)p;                                 p += 512;
  int* padflag = (int*)p;                               p += 512;
  unsigned int* bar = (unsigned int*)p;                 p += 256;

  // h(0) = 0 and barrier counters = 0 (graph replays rerun these; self-contained)
  hipMemsetAsync(h_hi, 0, 2 * HBUF_BYTES, stream);  // h_hi and h_lo are contiguous
  hipMemsetAsync(bar, 0, 256, stream);

  prep_kernel<<<1, 128, 0, stream>>>(x, tstar, padflag);
  gather_kernel<<<(Tn * Bn * EPn) / 256, 256, 0, stream>>>(x, embed, inp);
  wihcvt_kernel<<<(4 * Hn * EPn) / 256, 256, 0, stream>>>(Wih, wih_bf);
  lstm_scan<<<NBLK, 256, 0, stream>>>(Whh, wih_bf, bih, bhh, inp, tstar, padflag, h_hi,
                                      h_lo, hsel, bar);
  head_kernel<<<Bn, 64, 0, stream>>>(hsel, Wout, bout, out);
}

// Round 4
// 4836.130 us; speedup vs baseline: 3.7934x; 1.0388x over previous
//
#include <hip/hip_runtime.h>
#include <stdint.h>

#define Bn 128
#define Tn 256
#define En 300
#define EPn 320          // E padded to multiple of 32 (MFMA K)
#define Hn 1024
#define PADIDX 1
#define NBLK 256         // 2 groups x 128 col-blocks

typedef short s16x8 __attribute__((ext_vector_type(8)));
typedef float f32x4 __attribute__((ext_vector_type(4)));
typedef unsigned long long u64;
typedef unsigned int u32;

#define LDQ(p) __hip_atomic_load((p), __ATOMIC_RELAXED, __HIP_MEMORY_SCOPE_SYSTEM)
#define ST32(p, v) __hip_atomic_store((p), (v), __ATOMIC_RELAXED, __HIP_MEMORY_SCOPE_SYSTEM)

__device__ __forceinline__ unsigned short f2bf(float f) {
  u32 u = __builtin_bit_cast(u32, f);
  u32 r = (u + 0x7fffu + ((u >> 16) & 1u)) >> 16;  // RNE
  return (unsigned short)r;
}
__device__ __forceinline__ float bf2f(unsigned short h) {
  u32 u = ((u32)h) << 16;
  return __builtin_bit_cast(float, u);
}
__device__ __forceinline__ float sigmoidf_(float x) { return 1.f / (1.f + __expf(-x)); }
__device__ __forceinline__ float tanhf_(float x) { return 1.f - 2.f / (__expf(2.f * x) + 1.f); }

__device__ __forceinline__ s16x8 mkv(u64 a, u64 b) {
  union { u64 q[2]; s16x8 v; } u;
  u.q[0] = a; u.q[1] = b;
  return u.v;
}

// lane holds gate `gate` value v for its (b,unit); recover all 4 gates via shfl
__device__ __forceinline__ float gate_update(float pre, float& c, int gate) {
  float v = (gate == 2) ? tanhf_(pre) : sigmoidf_(pre);
  float vB = __shfl_xor(v, 4);
  float vC = __shfl_xor(v, 8);
  float vD = __shfl_xor(vB, 8);
  float i_ = (gate & 2) ? ((gate & 1) ? vD : vC) : ((gate & 1) ? vB : v);
  float f_ = (gate & 2) ? ((gate & 1) ? vC : vD) : ((gate & 1) ? v : vB);
  float g_ = (gate & 2) ? ((gate & 1) ? vB : v) : ((gate & 1) ? vD : vC);
  float o_ = (gate & 2) ? ((gate & 1) ? v : vB) : ((gate & 1) ? vC : vD);
  float cn = f_ * c + i_ * g_;
  c = cn;
  return o_ * tanhf_(cn);
}

// ---------------- K0: lengths -> tstar / padflag ----------------
__global__ void prep_kernel(const int* __restrict__ x, int* __restrict__ tstar,
                            int* __restrict__ padflag) {
  int b = threadIdx.x;
  if (b < Bn) {
    int len = 0;
    for (int t = 0; t < Tn; ++t) len += (x[b * Tn + t] != PADIDX) ? 1 : 0;
    int ts = (len > 0) ? (len - 1) : (Tn - 1);  // jax wraps index -1
    tstar[b] = ts;
    padflag[b] = (x[b * Tn + ts] == PADIDX) ? 1 : 0;
  }
}

// ---------------- K1: inp[t][b][k] = bf16(embed[x[b,t]][k]), k>=300 -> 0 ----
__global__ void gather_kernel(const int* __restrict__ x, const float* __restrict__ embed,
                              unsigned short* __restrict__ inp) {
  int idx = blockIdx.x * 256 + threadIdx.x;   // total = Tn*Bn*EPn
  int k = idx % EPn;
  int rem = idx / EPn;          // t*Bn + b
  int b = rem & (Bn - 1);
  int t = rem >> 7;
  int tok = x[b * Tn + t];
  float v = (k < En) ? embed[(size_t)tok * En + k] : 0.f;
  inp[idx] = f2bf(v);
}

// ---------------- K1b: W_ih -> bf16, K padded to 320 ----------------
__global__ void wihcvt_kernel(const float* __restrict__ Wih, unsigned short* __restrict__ wih_bf) {
  int idx = blockIdx.x * 256 + threadIdx.x;   // total = 4096*EPn
  int k = idx % EPn;
  int g = idx / EPn;
  float v = (k < En) ? Wih[(size_t)g * En + k] : 0.f;
  wih_bf[idx] = f2bf(v);
}

// ---------------- K2: persistent LSTM scan ----------------
// 256 blocks x 320 thr (4 compute waves + 1 extra). group = bid>>7 (64 batches);
// 128 col-blocks/group, each 8 hidden units. W_hh hi/lo in 128 KB LDS.
// Sync: per-WAVE monotone flags (no atomics) + leader-wave aggregation publishing
// one `go` word per group. NO __syncthreads in the steady-state loop.
__global__ __launch_bounds__(320, 1) void lstm_scan(
    const float* __restrict__ Whh, const unsigned short* __restrict__ wih_bf,
    const float* __restrict__ bih, const float* __restrict__ bhh,
    const unsigned short* __restrict__ inp, const int* __restrict__ tstar,
    const int* __restrict__ padflag, unsigned short* __restrict__ h_hi,
    unsigned short* __restrict__ h_lo, float* __restrict__ hsel,
    u32* __restrict__ flags, u32* __restrict__ go) {
  __shared__ unsigned short lds_hi[32 * Hn];   // 64 KB, XOR-swizzled rows
  __shared__ unsigned short lds_lo[32 * Hn];   // 64 KB

  const int bid = blockIdx.x;
  const int group = bid >> 7;              // 0: batches 0-63, 1: batches 64-127
  const int cb = bid & 127;                // col-block within group
  const int u0 = cb * 8;                   // 8 hidden units per block
  const int tid = threadIdx.x;

  // --- convert W_hh slice into LDS hi/lo (row c = ct*16 + gate*4 + usub) ---
  for (int i = tid; i < 32 * Hn; i += 320) {
    int c = i >> 10, k = i & (Hn - 1);
    int grow = ((c >> 2) & 3) * Hn + u0 + ((c >> 4) << 2) + (c & 3);
    float w = Whh[(size_t)grow * Hn + k];
    unsigned short hi = f2bf(w);
    unsigned short lo = f2bf(w - bf2f(hi));
    u32 byte = ((u32)(c * 2048 + k * 2)) ^ (((u32)(c & 7)) << 4);
    lds_hi[byte >> 1] = hi;
    lds_lo[byte >> 1] = lo;
  }
  __syncthreads();   // the ONLY block barrier; must precede any wave exit

  const int wv = tid >> 6, l = tid & 63;
  u32* const gop = go + group * 32;        // group's go word (own cache line)
  u32* const fbase = flags + group * 512;  // group's 512 per-wave flags

  if (wv == 4) {
    if (cb == 0) {
      // ---- leader wave: aggregate 512 flags, publish go = t ----
      for (int t = 1; t < Tn; ++t) {
        u32 spins = 0;
        for (;;) {
          int ok = 1;
#pragma unroll
          for (int i = 0; i < 8; ++i) ok &= (LDQ(fbase + l + 64 * i) >= (u32)t);
          if (__ballot(ok) == ~0ull) break;
          __builtin_amdgcn_s_sleep(1);
          if (++spins > 400000u) break;    // watchdog: dead unless deadlock
        }
        if (l == 0) ST32(gop, (u32)t);
      }
    }
    return;   // extra wave of every other block exits
  }

  const int lr = l & 15;                    // A-row (batch) / D-col in tile
  const int lq = l >> 4;                    // quadrant
  const int usub = lr & 3, gate = lr >> 2;
  const int b0w = group * 64 + wv * 16;     // this wave's 16 batch rows
  const u32 wswz = ((u32)(lr & 7)) << 4;
  const int col0 = gate * Hn + u0 + usub;   // ct=0 gate column; ct=1 is col0+4
  const float bias0 = bih[col0] + bhh[col0];
  const float bias1 = bih[col0 + 4] + bhh[col0 + 4];
  const int lq2 = lq * 2;
  u32* const myflag = fbase + (cb << 2) + wv;

  int tsr[4], pfr[4];
#pragma unroll
  for (int r = 0; r < 4; ++r) {
    int b = b0w + lq * 4 + r;
    tsr[r] = tstar[b];
    pfr[r] = padflag[b];
  }
  float creg0[4] = {0.f, 0.f, 0.f, 0.f};
  float creg1[4] = {0.f, 0.f, 0.f, 0.f};

  const char* base_hi = (const char*)lds_hi;
  const char* base_lo = (const char*)lds_lo;

  for (int t = 0; t < Tn; ++t) {
    const int pin = t & 1, pout = pin ^ 1;
    f32x4 acc0 = {bias0, bias0, bias0, bias0};
    f32x4 acc1 = {bias1, bias1, bias1, bias1};

    // ---- x-projection FIRST (h-independent): overlaps the go wait ----
    const unsigned short* ip = inp + ((size_t)t * Bn + b0w + lr) * EPn + lq * 8;
    const unsigned short* wp0 = wih_bf + (size_t)col0 * EPn + lq * 8;
#pragma unroll
    for (int ks = 0; ks < EPn / 32; ++ks) {
      s16x8 a = *(const s16x8*)(ip + ks * 32);
      s16x8 b0 = *(const s16x8*)(wp0 + ks * 32);
      s16x8 b1 = *(const s16x8*)(wp0 + 4 * EPn + ks * 32);
      acc0 = __builtin_amdgcn_mfma_f32_16x16x32_bf16(a, b0, acc0, 0, 0, 0);
      acc1 = __builtin_amdgcn_mfma_f32_16x16x32_bf16(a, b1, acc1, 0, 0, 0);
    }

    // ---- wait until all waves stored h(t) (t=0: go==0 passes) ----
    if (t) {
      u32 spins = 0;
      while (LDQ(gop) < (u32)t) {
        __builtin_amdgcn_s_sleep(2);
        if (++spins > 400000u) break;      // watchdog: dead unless deadlock
      }
    }

    // ---- recurrent: K = 1024, hi/lo split, coherent u64 loads,
    //      2-deep 4-ks register chunk pipeline ----
    const u64* hp = (const u64*)(h_hi + ((size_t)pin * Bn + b0w + lr) * Hn);
    const u64* lp = (const u64*)(h_lo + ((size_t)pin * Bn + b0w + lr) * Hn);

    u64 cka[16], ckb[16];
#define LOAD_CHUNK(C, KC)                                \
  _Pragma("unroll") for (int i = 0; i < 4; ++i) {        \
    int o = ((KC) * 4 + i) * 8 + lq2;                    \
    C[4 * i + 0] = LDQ(hp + o);                          \
    C[4 * i + 1] = LDQ(hp + o + 1);                      \
    C[4 * i + 2] = LDQ(lp + o);                          \
    C[4 * i + 3] = LDQ(lp + o + 1);                      \
  }
#define BODY(C, KC)                                                                   \
  _Pragma("unroll") for (int i = 0; i < 4; ++i) {                                     \
    int ks = (KC) * 4 + i;                                                            \
    s16x8 ahi = mkv(C[4 * i + 0], C[4 * i + 1]);                                      \
    s16x8 alo = mkv(C[4 * i + 2], C[4 * i + 3]);                                      \
    u32 o0 = ((u32)(lr * 2048 + (ks * 32 + lq * 8) * 2)) ^ wswz;                      \
    u32 o1 = o0 + 32768;                                                              \
    s16x8 bh0 = *(const s16x8*)(base_hi + o0);                                        \
    s16x8 bl0 = *(const s16x8*)(base_lo + o0);                                        \
    s16x8 bh1 = *(const s16x8*)(base_hi + o1);                                        \
    s16x8 bl1 = *(const s16x8*)(base_lo + o1);                                        \
    acc0 = __builtin_amdgcn_mfma_f32_16x16x32_bf16(ahi, bh0, acc0, 0, 0, 0);          \
    acc1 = __builtin_amdgcn_mfma_f32_16x16x32_bf16(ahi, bh1, acc1, 0, 0, 0);          \
    acc0 = __builtin_amdgcn_mfma_f32_16x16x32_bf16(alo, bh0, acc0, 0, 0, 0);          \
    acc1 = __builtin_amdgcn_mfma_f32_16x16x32_bf16(alo, bh1, acc1, 0, 0, 0);          \
    acc0 = __builtin_amdgcn_mfma_f32_16x16x32_bf16(ahi, bl0, acc0, 0, 0, 0);          \
    acc1 = __builtin_amdgcn_mfma_f32_16x16x32_bf16(ahi, bl1, acc1, 0, 0, 0);          \
  }

    LOAD_CHUNK(cka, 0)
    LOAD_CHUNK(ckb, 1)
    BODY(cka, 0) LOAD_CHUNK(cka, 2)
    BODY(ckb, 1) LOAD_CHUNK(ckb, 3)
    BODY(cka, 2) LOAD_CHUNK(cka, 4)
    BODY(ckb, 3) LOAD_CHUNK(ckb, 5)
    BODY(cka, 4) LOAD_CHUNK(cka, 6)
    BODY(ckb, 5) LOAD_CHUNK(ckb, 7)
    BODY(cka, 6)
    BODY(ckb, 7)
#undef LOAD_CHUNK
#undef BODY

    // ---- gates + state update (both col-tiles) ----
#pragma unroll
    for (int r = 0; r < 4; ++r) {
      float h0 = gate_update(acc0[r], creg0[r], gate);
      float h1 = gate_update(acc1[r], creg1[r], gate);
      // hi/lo bf16 split + pair-pack across usub lanes (convergent shfls)
      unsigned short h0h = f2bf(h0);
      unsigned short h0l = f2bf(h0 - bf2f(h0h));
      unsigned short h1h = f2bf(h1);
      unsigned short h1l = f2bf(h1 - bf2f(h1h));
      u32 n0h = (u32)__shfl_xor((int)(u32)h0h, 1);
      u32 n0l = (u32)__shfl_xor((int)(u32)h0l, 1);
      u32 n1h = (u32)__shfl_xor((int)(u32)h1h, 1);
      u32 n1l = (u32)__shfl_xor((int)(u32)h1l, 1);
      if (gate == 0) {
        int b = b0w + lq * 4 + r;
        size_t rowo = ((size_t)pout * Bn + b) * Hn;
        int j0 = u0 + usub, j1 = j0 + 4;
        if ((usub & 1) == 0) {  // even usub stores the (j, j+1) pair as one dword
          ST32((u32*)(h_hi + rowo + j0), (u32)h0h | (n0h << 16));
          ST32((u32*)(h_lo + rowo + j0), (u32)h0l | (n0l << 16));
          ST32((u32*)(h_hi + rowo + j1), (u32)h1h | (n1h << 16));
          ST32((u32*)(h_lo + rowo + j1), (u32)h1l | (n1l << 16));
        }
        if (t == tsr[r]) {
          hsel[(size_t)b * Hn + j0] = pfr[r] ? 0.f : h0;
          hsel[(size_t)b * Hn + j1] = pfr[r] ? 0.f : h1;
        }
      }
    }

    // ---- per-wave arrival flag: h(t+1) stored AND buf[t&1] reads retired ----
    asm volatile("s_waitcnt vmcnt(0)" ::: "memory");
    if (l == 0) ST32(myflag, (u32)(t + 1));
  }
}

// ---------------- K3: out[b][o] = hsel[b]·W_out[o] + b_out[o] ----------------
__global__ void head_kernel(const float* __restrict__ hsel, const float* __restrict__ Wout,
                            const float* __restrict__ bout, float* __restrict__ out) {
  int b = blockIdx.x;
  int l = threadIdx.x;  // 64 threads
  float s0 = 0.f, s1 = 0.f, s2 = 0.f;
  for (int j = l; j < Hn; j += 64) {
    float h = hsel[(size_t)b * Hn + j];
    s0 += h * Wout[j];
    s1 += h * Wout[Hn + j];
    s2 += h * Wout[2 * Hn + j];
  }
#pragma unroll
  for (int m = 32; m; m >>= 1) {
    s0 += __shfl_xor(s0, m);
    s1 += __shfl_xor(s1, m);
    s2 += __shfl_xor(s2, m);
  }
  if (l == 0) {
    out[b * 3 + 0] = s0 + bout[0];
    out[b * 3 + 1] = s1 + bout[1];
    out[b * 3 + 2] = s2 + bout[2];
  }
}

extern "C" void kernel_launch(void* const* d_in, const int* in_sizes, int n_in,
                              void* d_out, int out_size, void* d_ws, size_t ws_size,
                              hipStream_t stream) {
  const int* x = (const int*)d_in[0];
  const float* embed = (const float*)d_in[1];
  const float* Wih = (const float*)d_in[2];
  const float* Whh = (const float*)d_in[3];
  const float* bih = (const float*)d_in[4];
  const float* bhh = (const float*)d_in[5];
  const float* Wout = (const float*)d_in[6];
  const float* bout = (const float*)d_in[7];
  float* out = (float*)d_out;

  // ws layout
  const size_t INP_BYTES = (size_t)Tn * Bn * EPn * 2;       // 20,971,520
  const size_t WIH_BYTES = (size_t)4 * Hn * EPn * 2;        // 2,621,440
  const size_t HBUF_BYTES = (size_t)2 * Bn * Hn * 2;        // 524,288 each (hi, lo)
  const size_t HSEL_BYTES = (size_t)Bn * Hn * 4;            // 524,288
  char* p = (char*)d_ws;
  unsigned short* inp = (unsigned short*)p;             p += INP_BYTES;
  unsigned short* wih_bf = (unsigned short*)p;          p += WIH_BYTES;
  unsigned short* h_hi = (unsigned short*)p;            p += HBUF_BYTES;
  unsigned short* h_lo = (unsigned short*)p;            p += HBUF_BYTES;
  float* hsel = (float*)p;                              p += HSEL_BYTES;
  int* tstar = (int*)p;                                 p += 512;
  int* padflag = (int*)p;                               p += 512;
  u32* flags = (u32*)p;                                 p += 2 * 512 * 4;   // per-wave flags
  u32* go = (u32*)p;                                    p += 256;           // go words

  // h(0)=0, flags/go=0 each launch (graph replays rerun these; self-contained)
  hipMemsetAsync(h_hi, 0, 2 * HBUF_BYTES, stream);  // h_hi and h_lo are contiguous
  hipMemsetAsync(flags, 0, 2 * 512 * 4 + 256, stream);  // flags and go contiguous

  prep_kernel<<<1, 128, 0, stream>>>(x, tstar, padflag);
  gather_kernel<<<(Tn * Bn * EPn) / 256, 256, 0, stream>>>(x, embed, inp);
  wihcvt_kernel<<<(4 * Hn * EPn) / 256, 256, 0, stream>>>(Wih, wih_bf);
  lstm_scan<<<NBLK, 320, 0, stream>>>(Whh, wih_bf, bih, bhh, inp, tstar, padflag, h_hi,
                                      h_lo, hsel, flags, go);
  head_kernel<<<Bn, 64, 0, stream>>>(hsel, Wout, bout, out);
}